// Round 1
// baseline (1010.552 us; speedup 1.0000x reference)
//
#include <hip/hip_runtime.h>
#include <hip/hip_bf16.h>

#pragma clang fp contract(off)

typedef unsigned long long ull;

#define B_IMG   16
#define N_ELEM  1000000
#define PRE_NMS 2000
#define POST_NMS 1000
#define KEY_BITS 13
#define NBINS   (1 << KEY_BITS)       // 8192
#define KEY_SHIFT (32 - KEY_BITS)     // 19
#define CAP     4096
#define SORT_N  4096
#define KPAD    2048

// workspace layout (bytes)
#define OFF_HIST   0u                        // 16*8192*4   = 512KB
#define OFF_CNT    (512u*1024u)              // 16*4
#define OFF_KEYLO  (512u*1024u + 256u)       // 16*4
#define OFF_CAND   (1024u*1024u)             // 16*4096*8   = 512KB
#define OFF_BOXES  (1536u*1024u)             // 16*2048*8   = 256KB
#define OFF_VALID  (1792u*1024u)             // 16*32*8     = 4KB
#define OFF_DSPAN  (1800u*1024u)             // 16*2048*8   = 256KB
#define OFF_MAT    (2304u*1024u)             // 16*2048*32*8 = 8MB

__device__ __forceinline__ unsigned fkey(float f) {
  unsigned u = __float_as_uint(f);
  return (u & 0x80000000u) ? ~u : (u | 0x80000000u);
}

__device__ __forceinline__ ull shfl64(ull x, int src) {
  int lo = __shfl((int)(unsigned)(x & 0xffffffffull), src);
  int hi = __shfl((int)(unsigned)(x >> 32), src);
  return ((ull)(unsigned)hi << 32) | (ull)(unsigned)lo;
}

// ---------------- 1. per-image histogram of 13-bit keys ----------------
__global__ __launch_bounds__(512) void k_hist(const float* __restrict__ obj,
                                              unsigned* __restrict__ hist) {
  __shared__ unsigned h[NBINS];
  const int img = blockIdx.x >> 4;   // 16 blocks per image
  const int chunk = blockIdx.x & 15;
  for (int i = threadIdx.x; i < NBINS; i += 512) h[i] = 0u;
  __syncthreads();
  const int nv = N_ELEM / 4 / 16;    // 15625 float4 per chunk
  const float4* src = (const float4*)obj + (size_t)img * (N_ELEM / 4) + (size_t)chunk * nv;
  for (int v = threadIdx.x; v < nv; v += 512) {
    float4 x = src[v];
    atomicAdd(&h[fkey(x.x) >> KEY_SHIFT], 1u);
    atomicAdd(&h[fkey(x.y) >> KEY_SHIFT], 1u);
    atomicAdd(&h[fkey(x.z) >> KEY_SHIFT], 1u);
    atomicAdd(&h[fkey(x.w) >> KEY_SHIFT], 1u);
  }
  __syncthreads();
  unsigned* gh = hist + (size_t)img * NBINS;
  for (int i = threadIdx.x; i < NBINS; i += 512) {
    unsigned c = h[i];
    if (c) atomicAdd(&gh[i], c);
  }
}

// ---------------- 2. find per-image key threshold (2000th element's bin) ----------------
__global__ __launch_bounds__(256) void k_thresh(const unsigned* __restrict__ hist,
                                                unsigned* __restrict__ keylo) {
  const int img = blockIdx.x;
  const unsigned* gh = hist + (size_t)img * NBINS;
  __shared__ unsigned part[256];
  const int t = threadIdx.x;
  unsigned s = 0;
  const int hi = NBINS - 32 * t;     // exclusive top of this thread's region
  for (int b = hi - 32; b < hi; ++b) s += gh[b];
  part[t] = s;
  __syncthreads();
  if (t == 0) {
    unsigned acc = 0, excl = 0;
    int tstar = 255;
    for (int q = 0; q < 256; ++q) {
      unsigned na = acc + part[q];
      if (na >= PRE_NMS) { tstar = q; excl = acc; break; }
      acc = na;
    }
    const int bh = NBINS - 32 * tstar;
    unsigned a2 = excl, kl = 0;
    for (int b = bh - 1; b >= bh - 32; --b) {
      a2 += gh[b];
      if (a2 >= PRE_NMS) { kl = ((unsigned)b) << KEY_SHIFT; break; }
    }
    keylo[img] = kl;
  }
}

// ---------------- 3. compact candidates >= threshold ----------------
__global__ __launch_bounds__(512) void k_compact(const float* __restrict__ obj,
                                                 const unsigned* __restrict__ keylo,
                                                 unsigned* __restrict__ cnt,
                                                 ull* __restrict__ cand) {
  const int img = blockIdx.x >> 4;
  const int chunk = blockIdx.x & 15;
  const unsigned kl = keylo[img];
  const int nv = N_ELEM / 4 / 16;
  const float4* src = (const float4*)obj + (size_t)img * (N_ELEM / 4) + (size_t)chunk * nv;
  ull* cimg = cand + (size_t)img * CAP;
  const unsigned base_idx = (unsigned)chunk * (N_ELEM / 16);
  for (int v = threadIdx.x; v < nv; v += 512) {
    float4 x = src[v];
    unsigned k0 = fkey(x.x), k1 = fkey(x.y), k2 = fkey(x.z), k3 = fkey(x.w);
    unsigned bi = base_idx + 4u * (unsigned)v;
    if (k0 >= kl) { unsigned p = atomicAdd(&cnt[img], 1u); if (p < CAP) cimg[p] = ((ull)k0 << 32) | (unsigned)(~bi); }
    if (k1 >= kl) { unsigned p = atomicAdd(&cnt[img], 1u); if (p < CAP) cimg[p] = ((ull)k1 << 32) | (unsigned)(~(bi + 1u)); }
    if (k2 >= kl) { unsigned p = atomicAdd(&cnt[img], 1u); if (p < CAP) cimg[p] = ((ull)k2 << 32) | (unsigned)(~(bi + 2u)); }
    if (k3 >= kl) { unsigned p = atomicAdd(&cnt[img], 1u); if (p < CAP) cimg[p] = ((ull)k3 << 32) | (unsigned)(~(bi + 3u)); }
  }
}

// ---------------- 4. per-image bitonic sort + decode/clip/width-mask ----------------
__global__ __launch_bounds__(1024) void k_sortdecode(const ull* __restrict__ cand,
                                                     const unsigned* __restrict__ cnt,
                                                     const float2* __restrict__ delta,
                                                     const float2* __restrict__ anchor,
                                                     float2* __restrict__ boxes,
                                                     ull* __restrict__ validm) {
  __shared__ ull sk[SORT_N];
  const int img = blockIdx.x;
  unsigned M = cnt[img]; if (M > CAP) M = CAP;
  const ull* cimg = cand + (size_t)img * CAP;
  for (int i = threadIdx.x; i < SORT_N; i += 1024) sk[i] = (i < (int)M) ? cimg[i] : 0ull;
  __syncthreads();
  for (int k = 2; k <= SORT_N; k <<= 1) {
    for (int j = k >> 1; j > 0; j >>= 1) {
      for (int p = threadIdx.x; p < SORT_N / 2; p += 1024) {
        int i = ((p & ~(j - 1)) << 1) | (p & (j - 1));
        int ixj = i | j;
        ull a = sk[i], b = sk[ixj];
        bool asc = (i & k) != 0;
        bool sw = asc ? (a > b) : (a < b);   // overall descending
        if (sw) { sk[i] = b; sk[ixj] = a; }
      }
      __syncthreads();
    }
  }
  // decode top PRE_NMS, write padded boxes + validity ballot
  for (int i = threadIdx.x; i < KPAD; i += 1024) {
    float bx0 = 0.f, bx1 = 0.f;
    bool valid = false;
    if (i < PRE_NMS) {
      ull e = sk[i];
      unsigned idx = ~((unsigned)e);
      float2 d = delta[(size_t)img * N_ELEM + idx];
      float2 a = anchor[(size_t)img * N_ELEM + idx];
      float aw = a.y - a.x;
      float ac = a.x + 0.5f * aw;
      float dx = d.x;
      float dw = fminf(d.y, 4.135f);
      float pc = dx * aw + ac;
      float pw = expf(dw) * aw;
      float x0 = pc - 0.5f * pw;
      float x1 = pc + 0.5f * pw;
      x0 = fminf(fmaxf(x0, 0.f), 360.f);
      x1 = fminf(fmaxf(x1, 0.f), 360.f);
      bx0 = x0; bx1 = x1;
      valid = (x1 - x0) >= 10.0f;
    }
    boxes[(size_t)img * KPAD + i] = make_float2(bx0, bx1);
    ull bm = __ballot(valid);
    if ((threadIdx.x & 63) == 0) validm[img * 32 + (i >> 6)] = bm;
  }
}

// ---------------- 5. suppression bit-matrix (j > i  &  IoU > 0.7) ----------------
__global__ __launch_bounds__(256) void k_matrix(const float2* __restrict__ boxes,
                                                ull* __restrict__ mat,
                                                ull* __restrict__ dspan) {
  __shared__ float2 lb[KPAD];
  const int img = blockIdx.x >> 3;
  const int part = blockIdx.x & 7;
  const float2* bsrc = boxes + (size_t)img * KPAD;
  for (int i = threadIdx.x; i < KPAD; i += 256) lb[i] = bsrc[i];
  __syncthreads();
  ull* mimg = mat + (size_t)img * KPAD * 32;
  for (int q = threadIdx.x; q < 8192; q += 256) {
    int wid = part * 8192 + q;
    int i = wid >> 5, w = wid & 31;
    if (i >= PRE_NMS) continue;
    float2 b0 = lb[i];
    float a0 = b0.y - b0.x;
    int j0 = w << 6;
    ull bits = 0ull;
    if (j0 + 63 > i) {
      for (int jj = 0; jj < 64; ++jj) {
        int j = j0 + jj;
        if (j > i) {
          float2 b1 = lb[j];
          float lo = fmaxf(b0.x, b1.x);
          float hi = fminf(b0.y, b1.y);
          float inter = fmaxf(hi - lo, 0.f);
          float den = fmaxf((a0 + (b1.y - b1.x)) - inter, 1e-8f);
          float iou = inter / den;
          if (iou > 0.7f) bits |= (1ull << jj);
        }
      }
    }
    mimg[(size_t)i * 32 + w] = bits;
    if (w == (i >> 6)) dspan[(size_t)img * KPAD + i] = bits;
  }
}

// ---------------- 6. serial greedy scan + compact output ----------------
#define CH 16
#define NCHUNK 125   // ceil(2000/16)

__global__ __launch_bounds__(64) void k_scan(const ull* __restrict__ mat,
                                             const ull* __restrict__ dspan,
                                             const ull* __restrict__ validm,
                                             const float2* __restrict__ boxes,
                                             float2* __restrict__ out) {
  const int img = blockIdx.x;
  const int lane = threadIdx.x;
  const int w = lane & 31;
  ull removed = ~validm[img * 32 + w];
  const ull* Mr = mat + (size_t)img * KPAD * 32 + w;
  const ull* D = dspan + (size_t)img * KPAD;
  ull cur = 0ull;

  ull rA[CH], rB[CH], rC[CH];

  auto LOADF = [&](ull* r, int c) {
    const ull* p = Mr + (size_t)c * CH * 32;
#pragma unroll
    for (int u = 0; u < CH; ++u) r[u] = p[(size_t)u * 32];
  };
  auto PROCF = [&](ull* r, int c) {
    if ((c & 3) == 0) cur = shfl64(removed, c >> 2);
#pragma unroll
    for (int u = 0; u < CH; ++u) {
      int i = c * CH + u;
      int t = i & 63;
      ull dead = (cur >> t) & 1ull;
      ull m = dead ? 0ull : ~0ull;
      ull sr = D[i];
      cur |= sr & m;
      removed |= r[u] & m;
    }
  };

  LOADF(rA, 0);
  LOADF(rB, 1);
  for (int g = 0; g <= 120; g += 3) {
    LOADF(rC, g + 2); PROCF(rA, g);
    LOADF(rA, g + 3); PROCF(rB, g + 1);
    LOADF(rB, g + 4); PROCF(rC, g + 2);
  }
  PROCF(rA, 123);
  PROCF(rB, 124);

  // keep mask = ~removed (bits i>=2000 are removed via validity)
  ull keep = ~removed;
  int cw = (lane < 32) ? __popcll(keep) : 0;
  int v = cw;
#pragma unroll
  for (int off = 1; off < 64; off <<= 1) {
    int n = __shfl_up(v, off);
    if (lane >= off) v += n;
  }
  int excl = v - cw;
  int total = __shfl(v, 63);
  if (lane < 32) {
    int r = excl;
    ull kk = keep;
    while (kk) {
      int t = __ffsll(kk) - 1;
      kk &= kk - 1;
      if (r < POST_NMS) {
        out[(size_t)img * POST_NMS + r] = boxes[(size_t)img * KPAD + (w * 64 + t)];
      }
      ++r;
    }
  }
  for (int r = total + lane; r < POST_NMS; r += 64) {
    out[(size_t)img * POST_NMS + r] = make_float2(0.f, 0.f);
  }
}

extern "C" void kernel_launch(void* const* d_in, const int* in_sizes, int n_in,
                              void* d_out, int out_size, void* d_ws, size_t ws_size,
                              hipStream_t stream) {
  const float* obj = (const float*)d_in[0];
  const float2* delta = (const float2*)d_in[1];
  const float2* anchor = (const float2*)d_in[2];
  float2* out = (float2*)d_out;
  char* ws = (char*)d_ws;

  unsigned* hist = (unsigned*)(ws + OFF_HIST);
  unsigned* cnt = (unsigned*)(ws + OFF_CNT);
  unsigned* keylo = (unsigned*)(ws + OFF_KEYLO);
  ull* cand = (ull*)(ws + OFF_CAND);
  float2* boxes = (float2*)(ws + OFF_BOXES);
  ull* validm = (ull*)(ws + OFF_VALID);
  ull* dspan = (ull*)(ws + OFF_DSPAN);
  ull* mat = (ull*)(ws + OFF_MAT);

  // zero hist + cnt (keylo overwritten)
  hipMemsetAsync(ws, 0, OFF_KEYLO + 4096, stream);

  k_hist<<<256, 512, 0, stream>>>(obj, hist);
  k_thresh<<<16, 256, 0, stream>>>(hist, keylo);
  k_compact<<<256, 512, 0, stream>>>(obj, keylo, cnt, cand);
  k_sortdecode<<<16, 1024, 0, stream>>>(cand, cnt, delta, anchor, boxes, validm);
  k_matrix<<<128, 256, 0, stream>>>(boxes, mat, dspan);
  k_scan<<<16, 64, 0, stream>>>(mat, dspan, validm, boxes, out);
}

// Round 2
// 668.582 us; speedup vs baseline: 1.5115x; 1.5115x over previous
//
#include <hip/hip_runtime.h>
#include <hip/hip_bf16.h>

#pragma clang fp contract(off)

typedef unsigned long long ull;

#define B_IMG   16
#define N_ELEM  1000000
#define PRE_NMS 2000
#define POST_NMS 1000
#define KEY_BITS 13
#define NBINS   (1 << KEY_BITS)       // 8192
#define KEY_SHIFT (32 - KEY_BITS)     // 19
#define CAP     4096
#define SORT_N  4096
#define KPAD    2048

// workspace layout (bytes)
#define OFF_HIST   0u                        // 16*8192*4   = 512KB
#define OFF_CNT    (512u*1024u)              // 16*4
#define OFF_KEYLO  (512u*1024u + 256u)       // 16*4
#define OFF_CAND   (1024u*1024u)             // 16*4096*8   = 512KB
#define OFF_BOXES  (1536u*1024u)             // 16*2048*8   = 256KB
#define OFF_VALID  (1792u*1024u)             // 16*32*8     = 4KB
#define OFF_DSPAN  (1800u*1024u)             // 16*2048*8   = 256KB
#define OFF_MAT    (2304u*1024u)             // 16*2048*32*8 = 8MB

__device__ __forceinline__ unsigned fkey(float f) {
  unsigned u = __float_as_uint(f);
  return (u & 0x80000000u) ? ~u : (u | 0x80000000u);
}

__device__ __forceinline__ ull shfl64(ull x, int src) {
  int lo = __shfl((int)(unsigned)(x & 0xffffffffull), src);
  int hi = __shfl((int)(unsigned)(x >> 32), src);
  return ((ull)(unsigned)hi << 32) | (ull)(unsigned)lo;
}

// ---------------- 1. per-image histogram of 13-bit keys ----------------
__global__ __launch_bounds__(512) void k_hist(const float* __restrict__ obj,
                                              unsigned* __restrict__ hist) {
  __shared__ unsigned h[NBINS];
  const int img = blockIdx.x >> 4;   // 16 blocks per image
  const int chunk = blockIdx.x & 15;
  for (int i = threadIdx.x; i < NBINS; i += 512) h[i] = 0u;
  __syncthreads();
  const int nv = N_ELEM / 4 / 16;    // 15625 float4 per chunk
  const float4* src = (const float4*)obj + (size_t)img * (N_ELEM / 4) + (size_t)chunk * nv;
  for (int v = threadIdx.x; v < nv; v += 512) {
    float4 x = src[v];
    atomicAdd(&h[fkey(x.x) >> KEY_SHIFT], 1u);
    atomicAdd(&h[fkey(x.y) >> KEY_SHIFT], 1u);
    atomicAdd(&h[fkey(x.z) >> KEY_SHIFT], 1u);
    atomicAdd(&h[fkey(x.w) >> KEY_SHIFT], 1u);
  }
  __syncthreads();
  unsigned* gh = hist + (size_t)img * NBINS;
  for (int i = threadIdx.x; i < NBINS; i += 512) {
    unsigned c = h[i];
    if (c) atomicAdd(&gh[i], c);
  }
}

// ---------------- 2. find per-image key threshold (2000th element's bin) ----------------
__global__ __launch_bounds__(256) void k_thresh(const unsigned* __restrict__ hist,
                                                unsigned* __restrict__ keylo) {
  const int img = blockIdx.x;
  const unsigned* gh = hist + (size_t)img * NBINS;
  __shared__ unsigned part[256];
  const int t = threadIdx.x;
  unsigned s = 0;
  const int hi = NBINS - 32 * t;     // exclusive top of this thread's region
  for (int b = hi - 32; b < hi; ++b) s += gh[b];
  part[t] = s;
  __syncthreads();
  if (t == 0) {
    unsigned acc = 0, excl = 0;
    int tstar = 255;
    for (int q = 0; q < 256; ++q) {
      unsigned na = acc + part[q];
      if (na >= PRE_NMS) { tstar = q; excl = acc; break; }
      acc = na;
    }
    const int bh = NBINS - 32 * tstar;
    unsigned a2 = excl, kl = 0;
    for (int b = bh - 1; b >= bh - 32; --b) {
      a2 += gh[b];
      if (a2 >= PRE_NMS) { kl = ((unsigned)b) << KEY_SHIFT; break; }
    }
    keylo[img] = kl;
  }
}

// ---------------- 3. compact candidates >= threshold ----------------
__global__ __launch_bounds__(512) void k_compact(const float* __restrict__ obj,
                                                 const unsigned* __restrict__ keylo,
                                                 unsigned* __restrict__ cnt,
                                                 ull* __restrict__ cand) {
  const int img = blockIdx.x >> 4;
  const int chunk = blockIdx.x & 15;
  const unsigned kl = keylo[img];
  const int nv = N_ELEM / 4 / 16;
  const float4* src = (const float4*)obj + (size_t)img * (N_ELEM / 4) + (size_t)chunk * nv;
  ull* cimg = cand + (size_t)img * CAP;
  const unsigned base_idx = (unsigned)chunk * (N_ELEM / 16);
  for (int v = threadIdx.x; v < nv; v += 512) {
    float4 x = src[v];
    unsigned k0 = fkey(x.x), k1 = fkey(x.y), k2 = fkey(x.z), k3 = fkey(x.w);
    unsigned bi = base_idx + 4u * (unsigned)v;
    if (k0 >= kl) { unsigned p = atomicAdd(&cnt[img], 1u); if (p < CAP) cimg[p] = ((ull)k0 << 32) | (unsigned)(~bi); }
    if (k1 >= kl) { unsigned p = atomicAdd(&cnt[img], 1u); if (p < CAP) cimg[p] = ((ull)k1 << 32) | (unsigned)(~(bi + 1u)); }
    if (k2 >= kl) { unsigned p = atomicAdd(&cnt[img], 1u); if (p < CAP) cimg[p] = ((ull)k2 << 32) | (unsigned)(~(bi + 2u)); }
    if (k3 >= kl) { unsigned p = atomicAdd(&cnt[img], 1u); if (p < CAP) cimg[p] = ((ull)k3 << 32) | (unsigned)(~(bi + 3u)); }
  }
}

// ---------------- 4. per-image bitonic sort + decode/clip/width-mask ----------------
__global__ __launch_bounds__(1024) void k_sortdecode(const ull* __restrict__ cand,
                                                     const unsigned* __restrict__ cnt,
                                                     const float2* __restrict__ delta,
                                                     const float2* __restrict__ anchor,
                                                     float2* __restrict__ boxes,
                                                     ull* __restrict__ validm) {
  __shared__ ull sk[SORT_N];
  const int img = blockIdx.x;
  unsigned M = cnt[img]; if (M > CAP) M = CAP;
  const ull* cimg = cand + (size_t)img * CAP;
  for (int i = threadIdx.x; i < SORT_N; i += 1024) sk[i] = (i < (int)M) ? cimg[i] : 0ull;
  __syncthreads();
  for (int k = 2; k <= SORT_N; k <<= 1) {
    for (int j = k >> 1; j > 0; j >>= 1) {
      for (int p = threadIdx.x; p < SORT_N / 2; p += 1024) {
        int i = ((p & ~(j - 1)) << 1) | (p & (j - 1));
        int ixj = i | j;
        ull a = sk[i], b = sk[ixj];
        bool asc = (i & k) != 0;
        bool sw = asc ? (a > b) : (a < b);   // overall descending
        if (sw) { sk[i] = b; sk[ixj] = a; }
      }
      __syncthreads();
    }
  }
  // decode top PRE_NMS, write padded boxes + validity ballot
  for (int i = threadIdx.x; i < KPAD; i += 1024) {
    float bx0 = 0.f, bx1 = 0.f;
    bool valid = false;
    if (i < PRE_NMS) {
      ull e = sk[i];
      unsigned idx = ~((unsigned)e);
      float2 d = delta[(size_t)img * N_ELEM + idx];
      float2 a = anchor[(size_t)img * N_ELEM + idx];
      float aw = a.y - a.x;
      float ac = a.x + 0.5f * aw;
      float dx = d.x;
      float dw = fminf(d.y, 4.135f);
      float pc = dx * aw + ac;
      float pw = expf(dw) * aw;
      float x0 = pc - 0.5f * pw;
      float x1 = pc + 0.5f * pw;
      x0 = fminf(fmaxf(x0, 0.f), 360.f);
      x1 = fminf(fmaxf(x1, 0.f), 360.f);
      bx0 = x0; bx1 = x1;
      valid = (x1 - x0) >= 10.0f;
    }
    boxes[(size_t)img * KPAD + i] = make_float2(bx0, bx1);
    ull bm = __ballot(valid);
    if ((threadIdx.x & 63) == 0) validm[img * 32 + (i >> 6)] = bm;
  }
}

// ---------------- 5. suppression bit-matrix, wave-per-64x64-tile ----------------
// One wave owns tile (RI, CJ): lane = column j within the tile, loop i = row.
// Row box broadcast via readlane (SGPR, no LDS). __ballot assembles the 64-bit
// suppression word for row i; lane i keeps it and stores after the loop.
// Lower-triangle tiles (CJ < RI) fast-path store zeros so k_scan is unchanged.
__global__ __launch_bounds__(256) void k_matrix(const float2* __restrict__ boxes,
                                                ull* __restrict__ mat,
                                                ull* __restrict__ dspan) {
  const int wid = blockIdx.x * 4 + (threadIdx.x >> 6);   // global wave/tile id
  const int lane = threadIdx.x & 63;
  const int img = wid >> 10;          // 32*32 tiles per image
  const int RI = (wid >> 5) & 31;
  const int CJ = wid & 31;
  ull* mimg = mat + (size_t)img * KPAD * 32;
  ull myword = 0ull;
  if (CJ >= RI) {
    const float2* bimg = boxes + (size_t)img * KPAD;
    float2 rb = bimg[RI * 64 + lane];   // row boxes (this lane holds row `lane`)
    float2 cb = bimg[CJ * 64 + lane];   // col box for this lane
    float acol = cb.y - cb.x;
    const bool diag = (RI == CJ);
#pragma unroll 8
    for (int i = 0; i < 64; ++i) {
      float b0x = __uint_as_float((unsigned)__builtin_amdgcn_readlane((int)__float_as_uint(rb.x), i));
      float b0y = __uint_as_float((unsigned)__builtin_amdgcn_readlane((int)__float_as_uint(rb.y), i));
      float a0 = b0y - b0x;
      float lo = fmaxf(b0x, cb.x);
      float hi = fminf(b0y, cb.y);
      float inter = fmaxf(hi - lo, 0.f);
      float den = fmaxf((a0 + acol) - inter, 1e-8f);
      bool sup = (inter / den) > 0.7f;
      if (diag) sup = sup && (lane > i);
      ull bm = __ballot(sup);
      if (lane == i) myword = bm;
    }
    if (diag) dspan[(size_t)img * KPAD + RI * 64 + lane] = myword;
  }
  mimg[(size_t)(RI * 64 + lane) * 32 + CJ] = myword;
}

// ---------------- 6. serial greedy scan + compact output ----------------
#define CH 16
#define NCHUNK 125   // ceil(2000/16)

__global__ __launch_bounds__(64) void k_scan(const ull* __restrict__ mat,
                                             const ull* __restrict__ dspan,
                                             const ull* __restrict__ validm,
                                             const float2* __restrict__ boxes,
                                             float2* __restrict__ out) {
  const int img = blockIdx.x;
  const int lane = threadIdx.x;
  const int w = lane & 31;
  ull removed = ~validm[img * 32 + w];
  const ull* Mr = mat + (size_t)img * KPAD * 32 + w;
  const ull* D = dspan + (size_t)img * KPAD;
  ull cur = 0ull;

  ull rA[CH], rB[CH], rC[CH];

  auto LOADF = [&](ull* r, int c) {
    const ull* p = Mr + (size_t)c * CH * 32;
#pragma unroll
    for (int u = 0; u < CH; ++u) r[u] = p[(size_t)u * 32];
  };
  auto PROCF = [&](ull* r, int c) {
    if ((c & 3) == 0) cur = shfl64(removed, c >> 2);
#pragma unroll
    for (int u = 0; u < CH; ++u) {
      int i = c * CH + u;
      int t = i & 63;
      ull dead = (cur >> t) & 1ull;
      ull m = dead ? 0ull : ~0ull;
      ull sr = D[i];
      cur |= sr & m;
      removed |= r[u] & m;
    }
  };

  LOADF(rA, 0);
  LOADF(rB, 1);
  for (int g = 0; g <= 120; g += 3) {
    LOADF(rC, g + 2); PROCF(rA, g);
    LOADF(rA, g + 3); PROCF(rB, g + 1);
    LOADF(rB, g + 4); PROCF(rC, g + 2);
  }
  PROCF(rA, 123);
  PROCF(rB, 124);

  // keep mask = ~removed (bits i>=2000 are removed via validity)
  ull keep = ~removed;
  int cw = (lane < 32) ? __popcll(keep) : 0;
  int v = cw;
#pragma unroll
  for (int off = 1; off < 64; off <<= 1) {
    int n = __shfl_up(v, off);
    if (lane >= off) v += n;
  }
  int excl = v - cw;
  int total = __shfl(v, 63);
  if (lane < 32) {
    int r = excl;
    ull kk = keep;
    while (kk) {
      int t = __ffsll(kk) - 1;
      kk &= kk - 1;
      if (r < POST_NMS) {
        out[(size_t)img * POST_NMS + r] = boxes[(size_t)img * KPAD + (w * 64 + t)];
      }
      ++r;
    }
  }
  for (int r = total + lane; r < POST_NMS; r += 64) {
    out[(size_t)img * POST_NMS + r] = make_float2(0.f, 0.f);
  }
}

extern "C" void kernel_launch(void* const* d_in, const int* in_sizes, int n_in,
                              void* d_out, int out_size, void* d_ws, size_t ws_size,
                              hipStream_t stream) {
  const float* obj = (const float*)d_in[0];
  const float2* delta = (const float2*)d_in[1];
  const float2* anchor = (const float2*)d_in[2];
  float2* out = (float2*)d_out;
  char* ws = (char*)d_ws;

  unsigned* hist = (unsigned*)(ws + OFF_HIST);
  unsigned* cnt = (unsigned*)(ws + OFF_CNT);
  unsigned* keylo = (unsigned*)(ws + OFF_KEYLO);
  ull* cand = (ull*)(ws + OFF_CAND);
  float2* boxes = (float2*)(ws + OFF_BOXES);
  ull* validm = (ull*)(ws + OFF_VALID);
  ull* dspan = (ull*)(ws + OFF_DSPAN);
  ull* mat = (ull*)(ws + OFF_MAT);

  // zero hist + cnt (keylo overwritten)
  hipMemsetAsync(ws, 0, OFF_KEYLO + 4096, stream);

  k_hist<<<256, 512, 0, stream>>>(obj, hist);
  k_thresh<<<16, 256, 0, stream>>>(hist, keylo);
  k_compact<<<256, 512, 0, stream>>>(obj, keylo, cnt, cand);
  k_sortdecode<<<16, 1024, 0, stream>>>(cand, cnt, delta, anchor, boxes, validm);
  k_matrix<<<4096, 256, 0, stream>>>(boxes, mat, dspan);
  k_scan<<<16, 64, 0, stream>>>(mat, dspan, validm, boxes, out);
}

// Round 3
// 276.706 us; speedup vs baseline: 3.6521x; 2.4162x over previous
//
#include <hip/hip_runtime.h>
#include <hip/hip_bf16.h>

#pragma clang fp contract(off)

typedef unsigned long long ull;

#define B_IMG   16
#define N_ELEM  1000000
#define PRE_NMS 2000
#define POST_NMS 1000
#define KEY_BITS 13
#define NBINS   (1 << KEY_BITS)       // 8192
#define KEY_SHIFT (32 - KEY_BITS)     // 19
#define CAP     4096
#define SORT_N  4096
#define KPAD    2048

// workspace layout (bytes)
#define OFF_HIST   0u                        // 16*8192*4   = 512KB
#define OFF_CNT    (512u*1024u)              // 16*4
#define OFF_KEYLO  (512u*1024u + 256u)       // 16*4
#define OFF_CAND   (1024u*1024u)             // 16*4096*8   = 512KB
#define OFF_BOXES  (1536u*1024u)             // 16*2048*8   = 256KB
#define OFF_VALID  (1792u*1024u)             // 16*32*8     = 4KB
#define OFF_DSPAN  (1800u*1024u)             // 16*2048*8   = 256KB
#define OFF_MAT    (2304u*1024u)             // 16*2048*32*8 = 8MB

__device__ __forceinline__ unsigned fkey(float f) {
  unsigned u = __float_as_uint(f);
  return (u & 0x80000000u) ? ~u : (u | 0x80000000u);
}

__device__ __forceinline__ ull shfl64(ull x, int src) {
  int lo = __shfl((int)(unsigned)(x & 0xffffffffull), src);
  int hi = __shfl((int)(unsigned)(x >> 32), src);
  return ((ull)(unsigned)hi << 32) | (ull)(unsigned)lo;
}

// ---------------- 1. per-image histogram of 13-bit keys ----------------
__global__ __launch_bounds__(512) void k_hist(const float* __restrict__ obj,
                                              unsigned* __restrict__ hist) {
  __shared__ unsigned h[NBINS];
  const int img = blockIdx.x >> 4;   // 16 blocks per image
  const int chunk = blockIdx.x & 15;
  for (int i = threadIdx.x; i < NBINS; i += 512) h[i] = 0u;
  __syncthreads();
  const int nv = N_ELEM / 4 / 16;    // 15625 float4 per chunk
  const float4* src = (const float4*)obj + (size_t)img * (N_ELEM / 4) + (size_t)chunk * nv;
  for (int v = threadIdx.x; v < nv; v += 512) {
    float4 x = src[v];
    atomicAdd(&h[fkey(x.x) >> KEY_SHIFT], 1u);
    atomicAdd(&h[fkey(x.y) >> KEY_SHIFT], 1u);
    atomicAdd(&h[fkey(x.z) >> KEY_SHIFT], 1u);
    atomicAdd(&h[fkey(x.w) >> KEY_SHIFT], 1u);
  }
  __syncthreads();
  unsigned* gh = hist + (size_t)img * NBINS;
  for (int i = threadIdx.x; i < NBINS; i += 512) {
    unsigned c = h[i];
    if (c) atomicAdd(&gh[i], c);
  }
}

// ---------------- 2. find per-image key threshold (2000th element's bin) ----------------
__global__ __launch_bounds__(256) void k_thresh(const unsigned* __restrict__ hist,
                                                unsigned* __restrict__ keylo) {
  const int img = blockIdx.x;
  const unsigned* gh = hist + (size_t)img * NBINS;
  __shared__ unsigned part[256];
  const int t = threadIdx.x;
  unsigned s = 0;
  const int hi = NBINS - 32 * t;     // exclusive top of this thread's region
  for (int b = hi - 32; b < hi; ++b) s += gh[b];
  part[t] = s;
  __syncthreads();
  if (t == 0) {
    unsigned acc = 0, excl = 0;
    int tstar = 255;
    for (int q = 0; q < 256; ++q) {
      unsigned na = acc + part[q];
      if (na >= PRE_NMS) { tstar = q; excl = acc; break; }
      acc = na;
    }
    const int bh = NBINS - 32 * tstar;
    unsigned a2 = excl, kl = 0;
    for (int b = bh - 1; b >= bh - 32; --b) {
      a2 += gh[b];
      if (a2 >= PRE_NMS) { kl = ((unsigned)b) << KEY_SHIFT; break; }
    }
    keylo[img] = kl;
  }
}

// ---------------- 3. compact candidates >= threshold (LDS-staged) ----------------
// Survivors appended to an LDS buffer via LDS atomics; ONE global atomicAdd per
// block reserves a range in cand[img]. Order is arbitrary — the bitonic sort on
// unique (key,~idx) keys makes the final result deterministic.
#define NCHUNKS 50
#define LCAP    1024

__global__ __launch_bounds__(512) void k_compact(const float* __restrict__ obj,
                                                 const unsigned* __restrict__ keylo,
                                                 unsigned* __restrict__ cnt,
                                                 ull* __restrict__ cand) {
  __shared__ ull lbuf[LCAP];
  __shared__ unsigned lcnt, sbase, slen;
  const int img = blockIdx.x / NCHUNKS;
  const int chunk = blockIdx.x % NCHUNKS;
  if (threadIdx.x == 0) lcnt = 0u;
  __syncthreads();
  const unsigned kl = keylo[img];
  const int nv = N_ELEM / 4 / NCHUNKS;   // 5000 float4 per chunk
  const float4* src = (const float4*)obj + (size_t)img * (N_ELEM / 4) + (size_t)chunk * nv;
  const unsigned base_idx = (unsigned)chunk * (N_ELEM / NCHUNKS);
  for (int v = threadIdx.x; v < nv; v += 512) {
    float4 x = src[v];
    unsigned k0 = fkey(x.x), k1 = fkey(x.y), k2 = fkey(x.z), k3 = fkey(x.w);
    unsigned bi = base_idx + 4u * (unsigned)v;
    if (k0 >= kl) { unsigned p = atomicAdd(&lcnt, 1u); if (p < LCAP) lbuf[p] = ((ull)k0 << 32) | (unsigned)(~bi); }
    if (k1 >= kl) { unsigned p = atomicAdd(&lcnt, 1u); if (p < LCAP) lbuf[p] = ((ull)k1 << 32) | (unsigned)(~(bi + 1u)); }
    if (k2 >= kl) { unsigned p = atomicAdd(&lcnt, 1u); if (p < LCAP) lbuf[p] = ((ull)k2 << 32) | (unsigned)(~(bi + 2u)); }
    if (k3 >= kl) { unsigned p = atomicAdd(&lcnt, 1u); if (p < LCAP) lbuf[p] = ((ull)k3 << 32) | (unsigned)(~(bi + 3u)); }
  }
  __syncthreads();
  if (threadIdx.x == 0) {
    unsigned n = lcnt; if (n > LCAP) n = LCAP;
    slen = n;
    sbase = n ? atomicAdd(&cnt[img], n) : 0u;
  }
  __syncthreads();
  ull* cimg = cand + (size_t)img * CAP;
  const unsigned b0 = sbase, n0 = slen;
  for (unsigned i = threadIdx.x; i < n0; i += 512) {
    unsigned p = b0 + i;
    if (p < CAP) cimg[p] = lbuf[i];
  }
}

// ---------------- 4. per-image bitonic sort + decode/clip/width-mask ----------------
__global__ __launch_bounds__(1024) void k_sortdecode(const ull* __restrict__ cand,
                                                     const unsigned* __restrict__ cnt,
                                                     const float2* __restrict__ delta,
                                                     const float2* __restrict__ anchor,
                                                     float2* __restrict__ boxes,
                                                     ull* __restrict__ validm) {
  __shared__ ull sk[SORT_N];
  const int img = blockIdx.x;
  unsigned M = cnt[img]; if (M > CAP) M = CAP;
  const ull* cimg = cand + (size_t)img * CAP;
  for (int i = threadIdx.x; i < SORT_N; i += 1024) sk[i] = (i < (int)M) ? cimg[i] : 0ull;
  __syncthreads();
  for (int k = 2; k <= SORT_N; k <<= 1) {
    for (int j = k >> 1; j > 0; j >>= 1) {
      for (int p = threadIdx.x; p < SORT_N / 2; p += 1024) {
        int i = ((p & ~(j - 1)) << 1) | (p & (j - 1));
        int ixj = i | j;
        ull a = sk[i], b = sk[ixj];
        bool asc = (i & k) != 0;
        bool sw = asc ? (a > b) : (a < b);   // overall descending
        if (sw) { sk[i] = b; sk[ixj] = a; }
      }
      __syncthreads();
    }
  }
  // decode top PRE_NMS, write padded boxes + validity ballot
  for (int i = threadIdx.x; i < KPAD; i += 1024) {
    float bx0 = 0.f, bx1 = 0.f;
    bool valid = false;
    if (i < PRE_NMS) {
      ull e = sk[i];
      unsigned idx = ~((unsigned)e);
      float2 d = delta[(size_t)img * N_ELEM + idx];
      float2 a = anchor[(size_t)img * N_ELEM + idx];
      float aw = a.y - a.x;
      float ac = a.x + 0.5f * aw;
      float dx = d.x;
      float dw = fminf(d.y, 4.135f);
      float pc = dx * aw + ac;
      float pw = expf(dw) * aw;
      float x0 = pc - 0.5f * pw;
      float x1 = pc + 0.5f * pw;
      x0 = fminf(fmaxf(x0, 0.f), 360.f);
      x1 = fminf(fmaxf(x1, 0.f), 360.f);
      bx0 = x0; bx1 = x1;
      valid = (x1 - x0) >= 10.0f;
    }
    boxes[(size_t)img * KPAD + i] = make_float2(bx0, bx1);
    ull bm = __ballot(valid);
    if ((threadIdx.x & 63) == 0) validm[img * 32 + (i >> 6)] = bm;
  }
}

// ---------------- 5. suppression bit-matrix, wave-per-64x64-tile ----------------
__global__ __launch_bounds__(256) void k_matrix(const float2* __restrict__ boxes,
                                                ull* __restrict__ mat,
                                                ull* __restrict__ dspan) {
  const int wid = blockIdx.x * 4 + (threadIdx.x >> 6);   // global wave/tile id
  const int lane = threadIdx.x & 63;
  const int img = wid >> 10;          // 32*32 tiles per image
  const int RI = (wid >> 5) & 31;
  const int CJ = wid & 31;
  ull* mimg = mat + (size_t)img * KPAD * 32;
  ull myword = 0ull;
  if (CJ >= RI) {
    const float2* bimg = boxes + (size_t)img * KPAD;
    float2 rb = bimg[RI * 64 + lane];   // row boxes (this lane holds row `lane`)
    float2 cb = bimg[CJ * 64 + lane];   // col box for this lane
    float acol = cb.y - cb.x;
    const bool diag = (RI == CJ);
#pragma unroll 8
    for (int i = 0; i < 64; ++i) {
      float b0x = __uint_as_float((unsigned)__builtin_amdgcn_readlane((int)__float_as_uint(rb.x), i));
      float b0y = __uint_as_float((unsigned)__builtin_amdgcn_readlane((int)__float_as_uint(rb.y), i));
      float a0 = b0y - b0x;
      float lo = fmaxf(b0x, cb.x);
      float hi = fminf(b0y, cb.y);
      float inter = fmaxf(hi - lo, 0.f);
      float den = fmaxf((a0 + acol) - inter, 1e-8f);
      bool sup = (inter / den) > 0.7f;
      if (diag) sup = sup && (lane > i);
      ull bm = __ballot(sup);
      if (lane == i) myword = bm;
    }
    if (diag) dspan[(size_t)img * KPAD + RI * 64 + lane] = myword;
  }
  mimg[(size_t)(RI * 64 + lane) * 32 + CJ] = myword;
}

// ---------------- 6. serial greedy scan + compact output ----------------
#define CH 16
#define NCHUNK 125   // ceil(2000/16)

__global__ __launch_bounds__(64) void k_scan(const ull* __restrict__ mat,
                                             const ull* __restrict__ dspan,
                                             const ull* __restrict__ validm,
                                             const float2* __restrict__ boxes,
                                             float2* __restrict__ out) {
  const int img = blockIdx.x;
  const int lane = threadIdx.x;
  const int w = lane & 31;
  ull removed = ~validm[img * 32 + w];
  const ull* Mr = mat + (size_t)img * KPAD * 32 + w;
  const ull* D = dspan + (size_t)img * KPAD;
  ull cur = 0ull;

  ull rA[CH], rB[CH], rC[CH];

  auto LOADF = [&](ull* r, int c) {
    const ull* p = Mr + (size_t)c * CH * 32;
#pragma unroll
    for (int u = 0; u < CH; ++u) r[u] = p[(size_t)u * 32];
  };
  auto PROCF = [&](ull* r, int c) {
    if ((c & 3) == 0) cur = shfl64(removed, c >> 2);
#pragma unroll
    for (int u = 0; u < CH; ++u) {
      int i = c * CH + u;
      int t = i & 63;
      ull dead = (cur >> t) & 1ull;
      ull m = dead ? 0ull : ~0ull;
      ull sr = D[i];
      cur |= sr & m;
      removed |= r[u] & m;
    }
  };

  LOADF(rA, 0);
  LOADF(rB, 1);
  for (int g = 0; g <= 120; g += 3) {
    LOADF(rC, g + 2); PROCF(rA, g);
    LOADF(rA, g + 3); PROCF(rB, g + 1);
    LOADF(rB, g + 4); PROCF(rC, g + 2);
  }
  PROCF(rA, 123);
  PROCF(rB, 124);

  // keep mask = ~removed (bits i>=2000 are removed via validity)
  ull keep = ~removed;
  int cw = (lane < 32) ? __popcll(keep) : 0;
  int v = cw;
#pragma unroll
  for (int off = 1; off < 64; off <<= 1) {
    int n = __shfl_up(v, off);
    if (lane >= off) v += n;
  }
  int excl = v - cw;
  int total = __shfl(v, 63);
  if (lane < 32) {
    int r = excl;
    ull kk = keep;
    while (kk) {
      int t = __ffsll(kk) - 1;
      kk &= kk - 1;
      if (r < POST_NMS) {
        out[(size_t)img * POST_NMS + r] = boxes[(size_t)img * KPAD + (w * 64 + t)];
      }
      ++r;
    }
  }
  for (int r = total + lane; r < POST_NMS; r += 64) {
    out[(size_t)img * POST_NMS + r] = make_float2(0.f, 0.f);
  }
}

extern "C" void kernel_launch(void* const* d_in, const int* in_sizes, int n_in,
                              void* d_out, int out_size, void* d_ws, size_t ws_size,
                              hipStream_t stream) {
  const float* obj = (const float*)d_in[0];
  const float2* delta = (const float2*)d_in[1];
  const float2* anchor = (const float2*)d_in[2];
  float2* out = (float2*)d_out;
  char* ws = (char*)d_ws;

  unsigned* hist = (unsigned*)(ws + OFF_HIST);
  unsigned* cnt = (unsigned*)(ws + OFF_CNT);
  unsigned* keylo = (unsigned*)(ws + OFF_KEYLO);
  ull* cand = (ull*)(ws + OFF_CAND);
  float2* boxes = (float2*)(ws + OFF_BOXES);
  ull* validm = (ull*)(ws + OFF_VALID);
  ull* dspan = (ull*)(ws + OFF_DSPAN);
  ull* mat = (ull*)(ws + OFF_MAT);

  // zero hist + cnt (keylo overwritten)
  hipMemsetAsync(ws, 0, OFF_KEYLO + 4096, stream);

  k_hist<<<256, 512, 0, stream>>>(obj, hist);
  k_thresh<<<16, 256, 0, stream>>>(hist, keylo);
  k_compact<<<16 * NCHUNKS, 512, 0, stream>>>(obj, keylo, cnt, cand);
  k_sortdecode<<<16, 1024, 0, stream>>>(cand, cnt, delta, anchor, boxes, validm);
  k_matrix<<<4096, 256, 0, stream>>>(boxes, mat, dspan);
  k_scan<<<16, 64, 0, stream>>>(mat, dspan, validm, boxes, out);
}

// Round 4
// 254.300 us; speedup vs baseline: 3.9739x; 1.0881x over previous
//
#include <hip/hip_runtime.h>
#include <hip/hip_bf16.h>

#pragma clang fp contract(off)

typedef unsigned long long ull;

#define B_IMG   16
#define N_ELEM  1000000
#define PRE_NMS 2000
#define POST_NMS 1000
#define KEY_BITS 13
#define NBINS   (1 << KEY_BITS)       // 8192
#define KEY_SHIFT (32 - KEY_BITS)     // 19
#define CAP     4096
#define SORT_N  4096
#define KPAD    2048

// workspace layout (bytes)
#define OFF_HIST   0u                        // 16*8192*4   = 512KB
#define OFF_CNT    (512u*1024u)              // 16*4
#define OFF_KEYLO  (512u*1024u + 256u)       // 16*4
#define OFF_CAND   (1024u*1024u)             // 16*4096*8   = 512KB
#define OFF_BOXES  (1536u*1024u)             // 16*2048*8   = 256KB
#define OFF_VALID  (1792u*1024u)             // 16*32*8     = 4KB
#define OFF_DSPAN  (1800u*1024u)             // 16*2048*8   = 256KB
#define OFF_MAT    (2304u*1024u)             // 16*2048*32*8 = 8MB

__device__ __forceinline__ unsigned fkey(float f) {
  unsigned u = __float_as_uint(f);
  return (u & 0x80000000u) ? ~u : (u | 0x80000000u);
}

__device__ __forceinline__ ull shfl64(ull x, int src) {
  int lo = __shfl((int)(unsigned)(x & 0xffffffffull), src);
  int hi = __shfl((int)(unsigned)(x >> 32), src);
  return ((ull)(unsigned)hi << 32) | (ull)(unsigned)lo;
}

// ---------------- 1. per-image histogram of 13-bit keys ----------------
__global__ __launch_bounds__(512) void k_hist(const float* __restrict__ obj,
                                              unsigned* __restrict__ hist) {
  __shared__ unsigned h[NBINS];
  const int img = blockIdx.x >> 4;   // 16 blocks per image
  const int chunk = blockIdx.x & 15;
  for (int i = threadIdx.x; i < NBINS; i += 512) h[i] = 0u;
  __syncthreads();
  const int nv = N_ELEM / 4 / 16;    // 15625 float4 per chunk
  const float4* src = (const float4*)obj + (size_t)img * (N_ELEM / 4) + (size_t)chunk * nv;
  for (int v = threadIdx.x; v < nv; v += 512) {
    float4 x = src[v];
    atomicAdd(&h[fkey(x.x) >> KEY_SHIFT], 1u);
    atomicAdd(&h[fkey(x.y) >> KEY_SHIFT], 1u);
    atomicAdd(&h[fkey(x.z) >> KEY_SHIFT], 1u);
    atomicAdd(&h[fkey(x.w) >> KEY_SHIFT], 1u);
  }
  __syncthreads();
  unsigned* gh = hist + (size_t)img * NBINS;
  for (int i = threadIdx.x; i < NBINS; i += 512) {
    unsigned c = h[i];
    if (c) atomicAdd(&gh[i], c);
  }
}

// ---------------- 2. find per-image key threshold (2000th element's bin) ----------------
__global__ __launch_bounds__(256) void k_thresh(const unsigned* __restrict__ hist,
                                                unsigned* __restrict__ keylo) {
  const int img = blockIdx.x;
  const unsigned* gh = hist + (size_t)img * NBINS;
  __shared__ unsigned part[256];
  const int t = threadIdx.x;
  unsigned s = 0;
  const int hi = NBINS - 32 * t;     // exclusive top of this thread's region
  for (int b = hi - 32; b < hi; ++b) s += gh[b];
  part[t] = s;
  __syncthreads();
  if (t == 0) {
    unsigned acc = 0, excl = 0;
    int tstar = 255;
    for (int q = 0; q < 256; ++q) {
      unsigned na = acc + part[q];
      if (na >= PRE_NMS) { tstar = q; excl = acc; break; }
      acc = na;
    }
    const int bh = NBINS - 32 * tstar;
    unsigned a2 = excl, kl = 0;
    for (int b = bh - 1; b >= bh - 32; --b) {
      a2 += gh[b];
      if (a2 >= PRE_NMS) { kl = ((unsigned)b) << KEY_SHIFT; break; }
    }
    keylo[img] = kl;
  }
}

// ---------------- 3. compact candidates >= threshold (LDS-staged) ----------------
#define NCHUNKS 50
#define LCAP    1024

__global__ __launch_bounds__(512) void k_compact(const float* __restrict__ obj,
                                                 const unsigned* __restrict__ keylo,
                                                 unsigned* __restrict__ cnt,
                                                 ull* __restrict__ cand) {
  __shared__ ull lbuf[LCAP];
  __shared__ unsigned lcnt, sbase, slen;
  const int img = blockIdx.x / NCHUNKS;
  const int chunk = blockIdx.x % NCHUNKS;
  if (threadIdx.x == 0) lcnt = 0u;
  __syncthreads();
  const unsigned kl = keylo[img];
  const int nv = N_ELEM / 4 / NCHUNKS;   // 5000 float4 per chunk
  const float4* src = (const float4*)obj + (size_t)img * (N_ELEM / 4) + (size_t)chunk * nv;
  const unsigned base_idx = (unsigned)chunk * (N_ELEM / NCHUNKS);
  for (int v = threadIdx.x; v < nv; v += 512) {
    float4 x = src[v];
    unsigned k0 = fkey(x.x), k1 = fkey(x.y), k2 = fkey(x.z), k3 = fkey(x.w);
    unsigned bi = base_idx + 4u * (unsigned)v;
    if (k0 >= kl) { unsigned p = atomicAdd(&lcnt, 1u); if (p < LCAP) lbuf[p] = ((ull)k0 << 32) | (unsigned)(~bi); }
    if (k1 >= kl) { unsigned p = atomicAdd(&lcnt, 1u); if (p < LCAP) lbuf[p] = ((ull)k1 << 32) | (unsigned)(~(bi + 1u)); }
    if (k2 >= kl) { unsigned p = atomicAdd(&lcnt, 1u); if (p < LCAP) lbuf[p] = ((ull)k2 << 32) | (unsigned)(~(bi + 2u)); }
    if (k3 >= kl) { unsigned p = atomicAdd(&lcnt, 1u); if (p < LCAP) lbuf[p] = ((ull)k3 << 32) | (unsigned)(~(bi + 3u)); }
  }
  __syncthreads();
  if (threadIdx.x == 0) {
    unsigned n = lcnt; if (n > LCAP) n = LCAP;
    slen = n;
    sbase = n ? atomicAdd(&cnt[img], n) : 0u;
  }
  __syncthreads();
  ull* cimg = cand + (size_t)img * CAP;
  const unsigned b0 = sbase, n0 = slen;
  for (unsigned i = threadIdx.x; i < n0; i += 512) {
    unsigned p = b0 + i;
    if (p < CAP) cimg[p] = lbuf[i];
  }
}

// ---------------- 4. per-image bitonic sort + decode/clip/width-mask ----------------
__global__ __launch_bounds__(1024) void k_sortdecode(const ull* __restrict__ cand,
                                                     const unsigned* __restrict__ cnt,
                                                     const float2* __restrict__ delta,
                                                     const float2* __restrict__ anchor,
                                                     float2* __restrict__ boxes,
                                                     ull* __restrict__ validm) {
  __shared__ ull sk[SORT_N];
  const int img = blockIdx.x;
  unsigned M = cnt[img]; if (M > CAP) M = CAP;
  const ull* cimg = cand + (size_t)img * CAP;
  for (int i = threadIdx.x; i < SORT_N; i += 1024) sk[i] = (i < (int)M) ? cimg[i] : 0ull;
  __syncthreads();
  for (int k = 2; k <= SORT_N; k <<= 1) {
    for (int j = k >> 1; j > 0; j >>= 1) {
      for (int p = threadIdx.x; p < SORT_N / 2; p += 1024) {
        int i = ((p & ~(j - 1)) << 1) | (p & (j - 1));
        int ixj = i | j;
        ull a = sk[i], b = sk[ixj];
        bool asc = (i & k) != 0;
        bool sw = asc ? (a > b) : (a < b);   // overall descending
        if (sw) { sk[i] = b; sk[ixj] = a; }
      }
      __syncthreads();
    }
  }
  // decode top PRE_NMS, write padded boxes + validity ballot
  for (int i = threadIdx.x; i < KPAD; i += 1024) {
    float bx0 = 0.f, bx1 = 0.f;
    bool valid = false;
    if (i < PRE_NMS) {
      ull e = sk[i];
      unsigned idx = ~((unsigned)e);
      float2 d = delta[(size_t)img * N_ELEM + idx];
      float2 a = anchor[(size_t)img * N_ELEM + idx];
      float aw = a.y - a.x;
      float ac = a.x + 0.5f * aw;
      float dx = d.x;
      float dw = fminf(d.y, 4.135f);
      float pc = dx * aw + ac;
      float pw = expf(dw) * aw;
      float x0 = pc - 0.5f * pw;
      float x1 = pc + 0.5f * pw;
      x0 = fminf(fmaxf(x0, 0.f), 360.f);
      x1 = fminf(fmaxf(x1, 0.f), 360.f);
      bx0 = x0; bx1 = x1;
      valid = (x1 - x0) >= 10.0f;
    }
    boxes[(size_t)img * KPAD + i] = make_float2(bx0, bx1);
    ull bm = __ballot(valid);
    if ((threadIdx.x & 63) == 0) validm[img * 32 + (i >> 6)] = bm;
  }
}

// ---------------- 5. suppression bit-matrix, wave-per-64x64-tile ----------------
__global__ __launch_bounds__(256) void k_matrix(const float2* __restrict__ boxes,
                                                ull* __restrict__ mat,
                                                ull* __restrict__ dspan) {
  const int wid = blockIdx.x * 4 + (threadIdx.x >> 6);   // global wave/tile id
  const int lane = threadIdx.x & 63;
  const int img = wid >> 10;          // 32*32 tiles per image
  const int RI = (wid >> 5) & 31;
  const int CJ = wid & 31;
  ull* mimg = mat + (size_t)img * KPAD * 32;
  ull myword = 0ull;
  if (CJ >= RI) {
    const float2* bimg = boxes + (size_t)img * KPAD;
    float2 rb = bimg[RI * 64 + lane];   // row boxes (this lane holds row `lane`)
    float2 cb = bimg[CJ * 64 + lane];   // col box for this lane
    float acol = cb.y - cb.x;
    const bool diag = (RI == CJ);
#pragma unroll 8
    for (int i = 0; i < 64; ++i) {
      float b0x = __uint_as_float((unsigned)__builtin_amdgcn_readlane((int)__float_as_uint(rb.x), i));
      float b0y = __uint_as_float((unsigned)__builtin_amdgcn_readlane((int)__float_as_uint(rb.y), i));
      float a0 = b0y - b0x;
      float lo = fmaxf(b0x, cb.x);
      float hi = fminf(b0y, cb.y);
      float inter = fmaxf(hi - lo, 0.f);
      float den = fmaxf((a0 + acol) - inter, 1e-8f);
      bool sup = (inter / den) > 0.7f;
      if (diag) sup = sup && (lane > i);
      ull bm = __ballot(sup);
      if (lane == i) myword = bm;
    }
    if (diag) dspan[(size_t)img * KPAD + RI * 64 + lane] = myword;
  }
  mimg[(size_t)(RI * 64 + lane) * 32 + CJ] = myword;
}

// ---------------- 6. serial greedy scan + compact output ----------------
// The serial chain is: per row i, dead = bit(i&63) of cur; cur |= D[i] if alive.
// Both the mat rows (r) AND the dspan words (d) are prefetched 2 chunks ahead
// into static register arrays, so the chain is pure VALU (~16 cyc/row).
// sched_barrier(0) pins LOAD-before-PROC program order so the compiler can't
// sink loads back into the chain.
#define CH 16

__global__ __launch_bounds__(64) void k_scan(const ull* __restrict__ mat,
                                             const ull* __restrict__ dspan,
                                             const ull* __restrict__ validm,
                                             const float2* __restrict__ boxes,
                                             float2* __restrict__ out) {
  const int img = blockIdx.x;
  const int lane = threadIdx.x;
  const int w = lane & 31;
  ull removed = ~validm[img * 32 + w];
  const ull* Mr = mat + (size_t)img * KPAD * 32 + w;
  const ull* D = dspan + (size_t)img * KPAD;
  ull cur = 0ull;

  ull rA[CH], rB[CH], rC[CH];
  ull dA[CH], dB[CH], dC[CH];

#define LOADF(r, d, c) do {                                        \
    const ull* p_ = Mr + (size_t)(c) * CH * 32;                    \
    const ull* q_ = D + (size_t)(c) * CH;                          \
    _Pragma("unroll")                                              \
    for (int u = 0; u < CH; ++u) {                                 \
      r[u] = p_[(size_t)u * 32];                                   \
      d[u] = q_[u];                                                \
    }                                                              \
  } while (0)

#define PROCF(r, d, c) do {                                        \
    if (((c) & 3) == 0) cur = shfl64(removed, (c) >> 2);           \
    _Pragma("unroll")                                              \
    for (int u = 0; u < CH; ++u) {                                 \
      int t_ = ((c) & 3) * CH + u;                                 \
      ull dead_ = (cur >> t_) & 1ull;                              \
      ull m_ = dead_ ? 0ull : ~0ull;                               \
      cur |= d[u] & m_;                                            \
      removed |= r[u] & m_;                                        \
    }                                                              \
  } while (0)

  LOADF(rA, dA, 0);
  LOADF(rB, dB, 1);
  for (int g = 0; g <= 120; g += 3) {
    LOADF(rC, dC, g + 2); __builtin_amdgcn_sched_barrier(0); PROCF(rA, dA, g);
    LOADF(rA, dA, g + 3); __builtin_amdgcn_sched_barrier(0); PROCF(rB, dB, g + 1);
    LOADF(rB, dB, g + 4); __builtin_amdgcn_sched_barrier(0); PROCF(rC, dC, g + 2);
  }
  PROCF(rA, dA, 123);
  PROCF(rB, dB, 124);

#undef LOADF
#undef PROCF

  // keep mask = ~removed (bits i>=2000 are removed via validity)
  ull keep = ~removed;
  int cw = (lane < 32) ? __popcll(keep) : 0;
  int v = cw;
#pragma unroll
  for (int off = 1; off < 64; off <<= 1) {
    int n = __shfl_up(v, off);
    if (lane >= off) v += n;
  }
  int excl = v - cw;
  int total = __shfl(v, 63);
  if (lane < 32) {
    int r = excl;
    ull kk = keep;
    while (kk) {
      int t = __ffsll(kk) - 1;
      kk &= kk - 1;
      if (r < POST_NMS) {
        out[(size_t)img * POST_NMS + r] = boxes[(size_t)img * KPAD + (w * 64 + t)];
      }
      ++r;
    }
  }
  for (int r = total + lane; r < POST_NMS; r += 64) {
    out[(size_t)img * POST_NMS + r] = make_float2(0.f, 0.f);
  }
}

extern "C" void kernel_launch(void* const* d_in, const int* in_sizes, int n_in,
                              void* d_out, int out_size, void* d_ws, size_t ws_size,
                              hipStream_t stream) {
  const float* obj = (const float*)d_in[0];
  const float2* delta = (const float2*)d_in[1];
  const float2* anchor = (const float2*)d_in[2];
  float2* out = (float2*)d_out;
  char* ws = (char*)d_ws;

  unsigned* hist = (unsigned*)(ws + OFF_HIST);
  unsigned* cnt = (unsigned*)(ws + OFF_CNT);
  unsigned* keylo = (unsigned*)(ws + OFF_KEYLO);
  ull* cand = (ull*)(ws + OFF_CAND);
  float2* boxes = (float2*)(ws + OFF_BOXES);
  ull* validm = (ull*)(ws + OFF_VALID);
  ull* dspan = (ull*)(ws + OFF_DSPAN);
  ull* mat = (ull*)(ws + OFF_MAT);

  // zero hist + cnt (keylo overwritten)
  hipMemsetAsync(ws, 0, OFF_KEYLO + 4096, stream);

  k_hist<<<256, 512, 0, stream>>>(obj, hist);
  k_thresh<<<16, 256, 0, stream>>>(hist, keylo);
  k_compact<<<16 * NCHUNKS, 512, 0, stream>>>(obj, keylo, cnt, cand);
  k_sortdecode<<<16, 1024, 0, stream>>>(cand, cnt, delta, anchor, boxes, validm);
  k_matrix<<<4096, 256, 0, stream>>>(boxes, mat, dspan);
  k_scan<<<16, 64, 0, stream>>>(mat, dspan, validm, boxes, out);
}